// Round 10
// baseline (172.071 us; speedup 1.0000x reference)
//
#include <hip/hip_runtime.h>
#include <hip/hip_bf16.h>

#define TT 512
#define HH 1024
#define EE 32
#define KK 4
#define II 512
#define SS 2048

using f32x4 = __attribute__((ext_vector_type(4))) float;
using s16x8 = __attribute__((ext_vector_type(8))) short;
using f4v   = __attribute__((ext_vector_type(4))) float;

__device__ __forceinline__ unsigned short f2bf(float f){
  unsigned int u = __builtin_bit_cast(unsigned int, f);
  u += 0x7fffu + ((u >> 16) & 1u);
  return (unsigned short)(u >> 16);
}

typedef __attribute__((address_space(1))) const unsigned GUp;
typedef __attribute__((address_space(3))) unsigned LUp;
__device__ __forceinline__ void gload16(const void* g, void* l){
  __builtin_amdgcn_global_load_lds((GUp*)g, (LUp*)l, 16, 0, 0);
}

#define WAITV(N) asm volatile("s_waitcnt vmcnt(" #N ")" ::: "memory")
#define WAITL()  asm volatile("s_waitcnt lgkmcnt(0)" ::: "memory")
#define SBAR()   { __builtin_amdgcn_s_barrier(); __builtin_amdgcn_sched_barrier(0); }

// ---------------- router ----------------------------------------------------
__global__ __launch_bounds__(64) void k_router(
    const float* __restrict__ x, const float* __restrict__ Wg,
    unsigned short* __restrict__ xb, int* __restrict__ topk_idx,
    float* __restrict__ topk_w, float* __restrict__ sig_gate){
  int t = blockIdx.x; int l = threadIdx.x;
  const float* xr = x + (size_t)t * HH;
  #pragma unroll
  for(int i=0;i<HH/64;i++){
    int h = l + 64*i;
    xb[(size_t)t*HH + h] = f2bf(xr[h]);
  }
  float acc0=0.f, acc1=0.f, acc2=0.f, acc3=0.f;
  if(l < EE+1){
    const float* wcol = Wg + l;
    for(int h=0; h<HH; h+=4){
      acc0 += xr[h]   * wcol[(size_t)h*(EE+1)];
      acc1 += xr[h+1] * wcol[(size_t)(h+1)*(EE+1)];
      acc2 += xr[h+2] * wcol[(size_t)(h+2)*(EE+1)];
      acc3 += xr[h+3] * wcol[(size_t)(h+3)*(EE+1)];
    }
  }
  __shared__ float lg[EE+1];
  if(l < EE+1) lg[l] = (acc0+acc1)+(acc2+acc3);
  __syncthreads();
  if(l == 0){
    float v[EE];
    #pragma unroll
    for(int i=0;i<EE;i++) v[i]=lg[i];
    int idx[KK]; float val[KK];
    #pragma unroll
    for(int k=0;k<KK;k++){
      float m=-1e30f; int mi=0;
      for(int i=0;i<EE;i++){ if(v[i]>m){ m=v[i]; mi=i; } }
      idx[k]=mi; val[k]=m; v[mi]=-1e30f;
    }
    float mx = val[0], s=0.f; float w[KK];
    #pragma unroll
    for(int k=0;k<KK;k++){ w[k]=__expf(val[k]-mx); s+=w[k]; }
    float inv = 1.f/s;
    #pragma unroll
    for(int k=0;k<KK;k++){ topk_idx[t*KK+k]=idx[k]; topk_w[t*KK+k]=w[k]*inv; }
    sig_gate[t] = 1.f/(1.f+__expf(-lg[EE]));
  }
}

// ---------------- per-expert token list -------------------------------------
__global__ __launch_bounds__(64) void k_build(
    const int* __restrict__ topk_idx, const float* __restrict__ topk_w,
    int* __restrict__ token_list, float* __restrict__ weight_list,
    int* __restrict__ counts){
  int e = blockIdx.x; int l = threadIdx.x;
  int cnt = 0;
  for(int c=0;c<TT;c+=64){
    int t = c + l;
    int kk = -1;
    #pragma unroll
    for(int k=0;k<KK;k++) if(topk_idx[t*KK+k]==e) kk=k;
    unsigned long long b = __ballot(kk>=0);
    int pre = __popcll(b & ((1ull<<l)-1ull));
    if(kk>=0){
      token_list[e*TT + cnt + pre] = t;
      weight_list[e*TT + cnt + pre] = topk_w[t*KK+kk];
    }
    cnt += __popcll(b);
  }
  if(l==0) counts[e]=cnt;
}

__global__ __launch_bounds__(64) void k_scan(
    const int* __restrict__ counts, int* __restrict__ offs){
  if(threadIdx.x==0){
    int o=0;
    for(int e=0;e<EE;e++){ offs[e]=o; o+=counts[e]; }
  }
}

// ---------- convert fp32 [K][N] -> bf16 k8-packed [K/8][N][8] ---------------
// Grid-stride, no LDS/barriers. Thread task = (k-octet, 4 cols): reads 8x16B
// (warp: 1KB contiguous per row, NT), writes 64B contiguous (warp: 4KB).
__device__ __forceinline__ void cvt_span(const float* __restrict__ S,
    unsigned short* __restrict__ D, int N, int lgq, long ntask,
    long start, long stride){
  for(long i = start; i < ntask; i += stride){
    long oct = i >> lgq;
    int  cq  = (int)(i - (oct << lgq)) << 2;
    const float* p = S + (size_t)oct*8*N + cq;
    f4v r[8];
    #pragma unroll
    for(int k=0;k<8;k++)
      r[k] = __builtin_nontemporal_load((const f4v*)(p + (size_t)k*N));
    unsigned short* d = D + ((size_t)oct*N + cq)*8;
    #pragma unroll
    for(int j=0;j<4;j++){
      uint4 o;
      o.x = (unsigned)f2bf(r[0][j]) | ((unsigned)f2bf(r[1][j])<<16);
      o.y = (unsigned)f2bf(r[2][j]) | ((unsigned)f2bf(r[3][j])<<16);
      o.z = (unsigned)f2bf(r[4][j]) | ((unsigned)f2bf(r[5][j])<<16);
      o.w = (unsigned)f2bf(r[6][j]) | ((unsigned)f2bf(r[7][j])<<16);
      *reinterpret_cast<uint4*>(d + (size_t)j*8) = o;
    }
  }
}

// gate/up weight converts: 2048 blocks
__global__ __launch_bounds__(256) void k_cvt_gu(
    const float* __restrict__ Wsg, unsigned short* __restrict__ Bsg,
    const float* __restrict__ Wsu, unsigned short* __restrict__ Bsu,
    const float* __restrict__ Wgate, unsigned short* __restrict__ Bgate,
    const float* __restrict__ Wup, unsigned short* __restrict__ Bup){
  int bid = blockIdx.x, tid = threadIdx.x;
  if(bid < 128)
    cvt_span(Wsg, Bsg, SS, 9, 65536L, (long)bid*256 + tid, 128L*256);
  else if(bid < 256)
    cvt_span(Wsu, Bsu, SS, 9, 65536L, (long)(bid-128)*256 + tid, 128L*256);
  else if(bid < 1152)
    cvt_span(Wgate, Bgate, II, 7, 524288L, (long)(bid-256)*256 + tid, 896L*256);
  else
    cvt_span(Wup, Bup, II, 7, 524288L, (long)(bid-1152)*256 + tid, 896L*256);
}

// ============ DMA-ring GEMM core: C(64x64) += A(64xK)*B(Kx64) ===============
// 4-deep global_load_lds ring, counted vmcnt, K-step 32, 4 waves x 16 rows.
// LDS: A 4x4KB @0 (row 64B, seg src-swizzled s^((r>>1)&3) -> 2-way reads);
//      B(G) 4x4KB @16384, B(U) 4x4KB @32768 (col src-swizzled n^(q<<1)).
// Per thread per step: 3 DMA ops (dual) / 2 (single).
template<bool DUAL>
__device__ __forceinline__ void gemm64(
    const char* aSrc, const char* gSrc, const char* uSrc,
    long bStep, int NK, char* lds, int tid,
    f32x4 (&ag)[4], f32x4 (&au)[4])
{
  const int l = tid&63, w = tid>>6;
  const int mm = l&15, kt = l>>4;
  const int R = w*16 + mm;
  const unsigned aRd = (unsigned)(R*64 + ((kt ^ ((R>>1)&3))<<4));
  const unsigned bRd = (unsigned)(kt*1024 + ((mm ^ (kt<<1))<<4));
  char* aDst = lds + tid*16;
  char* gDst = lds + 16384 + tid*16;
  char* uDst = lds + 32768 + tid*16;

  WAITV(0);   // drain prior stores so counted vmcnt below is exact

#define ISSUE(s_) { const int sl_=(s_)&3;                                   \
    gload16(aSrc + (long)(s_)*64,    aDst + sl_*4096);                      \
    gload16(gSrc + (long)(s_)*bStep, gDst + sl_*4096);                      \
    if(DUAL){ gload16(uSrc + (long)(s_)*bStep, uDst + sl_*4096); } }

  ISSUE(0); ISSUE(1); ISSUE(2);
  for(int s=0; s<NK; s++){
    if(s+3 < NK){
      ISSUE(s+3);
      if constexpr(DUAL){ WAITV(9); } else { WAITV(6); }
    } else if(s+2 < NK){
      if constexpr(DUAL){ WAITV(6); } else { WAITV(4); }
    } else if(s+1 < NK){
      if constexpr(DUAL){ WAITV(3); } else { WAITV(2); }
    } else {
      WAITV(0);
    }
    SBAR();
    {
      const int sl = s&3;
      const char* Ab = lds + sl*4096;
      const char* Gb = lds + 16384 + sl*4096;
      const char* Ub = lds + 32768 + sl*4096;
      s16x8 af = *reinterpret_cast<const s16x8*>(Ab + aRd);
      #pragma unroll
      for(int c=0;c<4;c++){
        s16x8 bg = *reinterpret_cast<const s16x8*>(Gb + bRd + c*256);
        ag[c] = __builtin_amdgcn_mfma_f32_16x16x32_bf16(af, bg, ag[c], 0,0,0);
        if(DUAL){
          s16x8 bu = *reinterpret_cast<const s16x8*>(Ub + bRd + c*256);
          au[c] = __builtin_amdgcn_mfma_f32_16x16x32_bf16(af, bu, au[c], 0,0,0);
        }
      }
    }
    WAITL(); SBAR();
  }
#undef ISSUE
}

// ---------------- launch2: gemm_gu (512) + down-weight cvt (1024) -----------
__global__ __launch_bounds__(256) void k_gu(
    const unsigned short* __restrict__ xb,
    const unsigned short* __restrict__ Bsg, const unsigned short* __restrict__ Bsu,
    unsigned short* __restrict__ Hs,
    const unsigned short* __restrict__ Bgate, const unsigned short* __restrict__ Bup,
    const int* __restrict__ token_list, const int* __restrict__ counts,
    const int* __restrict__ offs, unsigned short* __restrict__ hbuf,
    const float* __restrict__ Wdown, unsigned short* __restrict__ Bdown,
    const float* __restrict__ Wsd, unsigned short* __restrict__ Bsd){
  __shared__ __align__(16) char lds[49152];
  int bid = blockIdx.x, tid = threadIdx.x;
  if(bid >= 512){
    int cb = bid - 512;
    if(cb < 896)
      cvt_span(Wdown, Bdown, HH, 8, 524288L, (long)cb*256 + tid, 896L*256);
    else
      cvt_span(Wsd, Bsd, HH, 8, 65536L, (long)(cb-896)*256 + tid, 128L*256);
    return;
  }
  const int w = tid>>6, l = tid&63;
  const int mm = l&15, kt = l>>4;
  const int ar = tid>>2;
  const int sseg = (tid&3) ^ ((ar>>1)&3);
  const int q = tid>>6, n = tid&63;
  const int nsrc = n ^ (q<<1);
  f32x4 zero = {0.f,0.f,0.f,0.f};
  f32x4 ag[4], au[4];

  if(bid < 256){
    int n0 = (bid & 31) * 64;
    int r0 = (bid >> 5) * 64;
    #pragma unroll
    for(int c=0;c<4;c++){ ag[c]=zero; au[c]=zero; }
    const char* aSrc = (const char*)xb + ((size_t)(r0+ar)*HH + sseg*8)*2;
    const char* gSrc = (const char*)Bsg + ((size_t)q*SS + n0 + nsrc)*16;
    const char* uSrc = (const char*)Bsu + ((size_t)q*SS + n0 + nsrc)*16;
    gemm64<true>(aSrc, gSrc, uSrc, (long)SS*64, HH/32, lds, tid, ag, au);
    #pragma unroll
    for(int c=0;c<4;c++){
      #pragma unroll
      for(int j=0;j<4;j++){
        int lrow = w*16 + kt*4 + j;
        float gg = ag[c][j], uu = au[c][j];
        Hs[(size_t)(r0+lrow)*SS + n0 + c*16 + mm] = f2bf(gg*uu/(1.f+__expf(-gg)));
      }
    }
  } else {
    int g = bid - 256;
    int e = g >> 3, i0 = (g & 7) * 64;
    int cnt = counts[e]; if(cnt == 0) return;
    int off = offs[e];
    const char* gBase = (const char*)(Bgate + (size_t)e*HH*II) + ((size_t)q*II + i0 + nsrc)*16;
    const char* uBase = (const char*)(Bup   + (size_t)e*HH*II) + ((size_t)q*II + i0 + nsrc)*16;
    for(int rt=0; rt*64<cnt; rt++){
      int nv = cnt - rt*64; if(nv > 64) nv = 64;
      int rr_ = ar < nv ? ar : nv-1;
      int tok = token_list[e*TT + rt*64 + rr_];
      #pragma unroll
      for(int c=0;c<4;c++){ ag[c]=zero; au[c]=zero; }
      const char* aSrc = (const char*)xb + ((size_t)tok*HH + sseg*8)*2;
      gemm64<true>(aSrc, gBase, uBase, (long)II*64, HH/32, lds, tid, ag, au);
      #pragma unroll
      for(int c=0;c<4;c++){
        #pragma unroll
        for(int j=0;j<4;j++){
          int lrow = w*16 + kt*4 + j;
          if(lrow < nv){
            float gg = ag[c][j], uu = au[c][j];
            hbuf[(size_t)(off+rt*64+lrow)*II + i0 + c*16 + mm] =
                f2bf(gg*uu/(1.f+__expf(-gg)));
          }
        }
      }
    }
  }
}

// ---------------- launch3: down (shared split-K x2 + expert), atomic --------
__global__ __launch_bounds__(256) void k_down(
    const unsigned short* __restrict__ Hs, const unsigned short* __restrict__ Bsd,
    const float* __restrict__ sig_gate,
    const unsigned short* __restrict__ hbuf, const unsigned short* __restrict__ Bdown,
    const int* __restrict__ token_list, const float* __restrict__ weight_list,
    const int* __restrict__ counts, const int* __restrict__ offs,
    float* __restrict__ out){
  __shared__ __align__(16) char lds[32768];
  int bid = blockIdx.x, tid = threadIdx.x;
  const int w = tid>>6, l = tid&63;
  const int mm = l&15, kt = l>>4;
  const int ar = tid>>2;
  const int sseg = (tid&3) ^ ((ar>>1)&3);
  const int q = tid>>6, n = tid&63;
  const int nsrc = n ^ (q<<1);
  f32x4 zero = {0.f,0.f,0.f,0.f};
  f32x4 acc[4], dummy[4];

  if(bid < 256){
    int rt_ = bid>>5, rem = bid&31;
    int nt_ = rem>>1, kc = rem&1;
    int r0 = rt_*64, n0 = nt_*64;
    #pragma unroll
    for(int c=0;c<4;c++) acc[c]=zero;
    const char* aSrc = (const char*)Hs + ((size_t)(r0+ar)*SS + kc*1024 + sseg*8)*2;
    const char* bSrc = (const char*)Bsd + ((size_t)(kc*128 + q)*HH + n0 + nsrc)*16;
    gemm64<false>(aSrc, bSrc, bSrc, (long)HH*64, 32, lds, tid, acc, dummy);
    #pragma unroll
    for(int c=0;c<4;c++){
      #pragma unroll
      for(int j=0;j<4;j++){
        int lrow = w*16 + kt*4 + j;
        atomicAdd(&out[(size_t)(r0+lrow)*HH + n0 + c*16 + mm],
                  sig_gate[r0+lrow]*acc[c][j]);
      }
    }
  } else {
    int b = bid - 256;
    int e = b >> 4, n0 = (b & 15) * 64;
    int cnt = counts[e]; if(cnt == 0) return;
    int off = offs[e];
    const char* bBase = (const char*)(Bdown + (size_t)e*II*HH) + ((size_t)q*HH + n0 + nsrc)*16;
    for(int rt=0; rt*64<cnt; rt++){
      int nv = cnt - rt*64; if(nv > 64) nv = 64;
      int rr_ = ar < nv ? ar : nv-1;
      #pragma unroll
      for(int c=0;c<4;c++) acc[c]=zero;
      const char* aSrc = (const char*)hbuf + ((size_t)(off+rt*64+rr_)*II + sseg*8)*2;
      gemm64<false>(aSrc, bBase, bBase, (long)HH*64, II/32, lds, tid, acc, dummy);
      #pragma unroll
      for(int c=0;c<4;c++){
        #pragma unroll
        for(int j=0;j<4;j++){
          int lrow = w*16 + kt*4 + j;
          if(lrow < nv){
            int t = token_list[e*TT + rt*64 + lrow];
            float wt = weight_list[e*TT + rt*64 + lrow];
            atomicAdd(&out[(size_t)t*HH + n0 + c*16 + mm], wt*acc[c][j]);
          }
        }
      }
    }
  }
}

extern "C" void kernel_launch(void* const* d_in, const int* in_sizes, int n_in,
                              void* d_out, int out_size, void* d_ws, size_t ws_size,
                              hipStream_t stream) {
  const float* x     = (const float*)d_in[0];
  const float* Wg    = (const float*)d_in[1];
  const float* Wgate = (const float*)d_in[2];
  const float* Wup   = (const float*)d_in[3];
  const float* Wdown = (const float*)d_in[4];
  const float* Wsg   = (const float*)d_in[5];
  const float* Wsu   = (const float*)d_in[6];
  const float* Wsd   = (const float*)d_in[7];
  float* out = (float*)d_out;

  char* ws = (char*)d_ws;
  unsigned short* xb   = (unsigned short*)ws; ws += (size_t)TT*HH*2;
  unsigned short* Hs   = (unsigned short*)ws; ws += (size_t)TT*SS*2;
  unsigned short* hbuf = (unsigned short*)ws; ws += (size_t)(TT*KK+128)*II*2;
  int*   token_list  = (int*)ws;   ws += (size_t)EE*TT*4;
  float* weight_list = (float*)ws; ws += (size_t)EE*TT*4;
  int*   topk_idx    = (int*)ws;   ws += (size_t)TT*KK*4;
  float* topk_wq     = (float*)ws; ws += (size_t)TT*KK*4;
  int*   counts      = (int*)ws;   ws += 128;
  int*   offsb       = (int*)ws;   ws += 128;
  float* sig_gate    = (float*)ws; ws += (size_t)TT*4;
  unsigned short* Bsg   = (unsigned short*)ws; ws += (size_t)HH*SS*2;
  unsigned short* Bsu   = (unsigned short*)ws; ws += (size_t)HH*SS*2;
  unsigned short* Bgate = (unsigned short*)ws; ws += (size_t)EE*HH*II*2;
  unsigned short* Bup   = (unsigned short*)ws; ws += (size_t)EE*HH*II*2;
  unsigned short* Bdown = (unsigned short*)ws; ws += (size_t)EE*II*HH*2;
  unsigned short* Bsd   = (unsigned short*)ws; ws += (size_t)SS*HH*2;

  hipMemsetAsync(d_out, 0, (size_t)TT*HH*4, stream);
  k_router<<<TT, 64, 0, stream>>>(x, Wg, xb, topk_idx, topk_wq, sig_gate);
  k_build<<<EE, 64, 0, stream>>>(topk_idx, topk_wq, token_list, weight_list, counts);
  k_scan<<<1, 64, 0, stream>>>(counts, offsb);
  k_cvt_gu<<<2048, 256, 0, stream>>>(Wsg, Bsg, Wsu, Bsu, Wgate, Bgate, Wup, Bup);
  k_gu<<<512 + 1024, 256, 0, stream>>>(
      xb, Bsg, Bsu, Hs, Bgate, Bup, token_list, counts, offsb, hbuf,
      Wdown, Bdown, Wsd, Bsd);
  k_down<<<256 + EE*(HH/64), 256, 0, stream>>>(
      Hs, Bsd, sig_gate, hbuf, Bdown, token_list, weight_list, counts, offsb, out);
}

// Round 11
// 148.940 us; speedup vs baseline: 1.1553x; 1.1553x over previous
//
#include <hip/hip_runtime.h>
#include <hip/hip_bf16.h>

#define TT 512
#define HH 1024
#define EE 32
#define KK 4
#define II 512
#define SS 2048

using f32x4 = __attribute__((ext_vector_type(4))) float;
using s16x8 = __attribute__((ext_vector_type(8))) short;
using f4v   = __attribute__((ext_vector_type(4))) float;

__device__ __forceinline__ unsigned short f2bf(float f){
  unsigned int u = __builtin_bit_cast(unsigned int, f);
  u += 0x7fffu + ((u >> 16) & 1u);
  return (unsigned short)(u >> 16);
}

typedef __attribute__((address_space(1))) const unsigned GUp;
typedef __attribute__((address_space(3))) unsigned LUp;
__device__ __forceinline__ void gload16(const void* g, void* l){
  __builtin_amdgcn_global_load_lds((GUp*)g, (LUp*)l, 16, 0, 0);
}

#define WAITV(N) asm volatile("s_waitcnt vmcnt(" #N ")" ::: "memory")
#define WAITL()  asm volatile("s_waitcnt lgkmcnt(0)" ::: "memory")
#define SBAR()   { __builtin_amdgcn_s_barrier(); __builtin_amdgcn_sched_barrier(0); }

// ---------------- router: logits + top-4 + gate (4-wave split reduction) ----
__global__ __launch_bounds__(256) void k_router(
    const float* __restrict__ x, const float* __restrict__ Wg,
    int* __restrict__ topk_idx, float* __restrict__ topk_w,
    float* __restrict__ sig_gate){
  int t = blockIdx.x;
  int tid = threadIdx.x, w = tid>>6, l = tid&63;
  __shared__ float part[4][EE+1];
  if(l < EE+1){
    const float* xr = x + (size_t)t*HH + w*256;
    const float* wc = Wg + (size_t)(w*256)*(EE+1) + l;
    float a0=0.f,a1=0.f,a2=0.f,a3=0.f,a4=0.f,a5=0.f,a6=0.f,a7=0.f;
    #pragma unroll
    for(int h=0; h<256; h+=8){
      a0 += xr[h  ] * wc[(size_t)(h  )*(EE+1)];
      a1 += xr[h+1] * wc[(size_t)(h+1)*(EE+1)];
      a2 += xr[h+2] * wc[(size_t)(h+2)*(EE+1)];
      a3 += xr[h+3] * wc[(size_t)(h+3)*(EE+1)];
      a4 += xr[h+4] * wc[(size_t)(h+4)*(EE+1)];
      a5 += xr[h+5] * wc[(size_t)(h+5)*(EE+1)];
      a6 += xr[h+6] * wc[(size_t)(h+6)*(EE+1)];
      a7 += xr[h+7] * wc[(size_t)(h+7)*(EE+1)];
    }
    part[w][l] = ((a0+a1)+(a2+a3)) + ((a4+a5)+(a6+a7));
  }
  __syncthreads();
  if(tid == 0){
    float v[EE];
    #pragma unroll
    for(int i=0;i<EE;i++)
      v[i] = (part[0][i]+part[1][i]) + (part[2][i]+part[3][i]);
    float lgate = (part[0][EE]+part[1][EE]) + (part[2][EE]+part[3][EE]);
    int idx[KK]; float val[KK];
    #pragma unroll
    for(int k=0;k<KK;k++){
      float m=-1e30f; int mi=0;
      for(int i=0;i<EE;i++){ if(v[i]>m){ m=v[i]; mi=i; } }
      idx[k]=mi; val[k]=m; v[mi]=-1e30f;
    }
    float mx = val[0], s=0.f; float ww[KK];
    #pragma unroll
    for(int k=0;k<KK;k++){ ww[k]=__expf(val[k]-mx); s+=ww[k]; }
    float inv = 1.f/s;
    #pragma unroll
    for(int k=0;k<KK;k++){ topk_idx[t*KK+k]=idx[k]; topk_w[t*KK+k]=ww[k]*inv; }
    sig_gate[t] = 1.f/(1.f+__expf(-lgate));
  }
}

// ---------------- per-expert token list -------------------------------------
__global__ __launch_bounds__(64) void k_build(
    const int* __restrict__ topk_idx, const float* __restrict__ topk_w,
    int* __restrict__ token_list, float* __restrict__ weight_list,
    int* __restrict__ counts){
  int e = blockIdx.x; int l = threadIdx.x;
  int cnt = 0;
  for(int c=0;c<TT;c+=64){
    int t = c + l;
    int kk = -1;
    #pragma unroll
    for(int k=0;k<KK;k++) if(topk_idx[t*KK+k]==e) kk=k;
    unsigned long long b = __ballot(kk>=0);
    int pre = __popcll(b & ((1ull<<l)-1ull));
    if(kk>=0){
      token_list[e*TT + cnt + pre] = t;
      weight_list[e*TT + cnt + pre] = topk_w[t*KK+kk];
    }
    cnt += __popcll(b);
  }
  if(l==0) counts[e]=cnt;
}

__global__ __launch_bounds__(64) void k_scan(
    const int* __restrict__ counts, int* __restrict__ offs){
  if(threadIdx.x==0){
    int o=0;
    for(int e=0;e<EE;e++){ offs[e]=o; o+=counts[e]; }
  }
}

// ---------- convert fp32 [K][N] -> bf16 k8-packed [K/8][N][8] ---------------
__device__ __forceinline__ void cvt_span(const float* __restrict__ S,
    unsigned short* __restrict__ D, int N, int lgq, long ntask,
    long start, long stride){
  for(long i = start; i < ntask; i += stride){
    long oct = i >> lgq;
    int  cq  = (int)(i - (oct << lgq)) << 2;
    const float* p = S + (size_t)oct*8*N + cq;
    f4v r[8];
    #pragma unroll
    for(int k=0;k<8;k++)
      r[k] = __builtin_nontemporal_load((const f4v*)(p + (size_t)k*N));
    unsigned short* d = D + ((size_t)oct*N + cq)*8;
    #pragma unroll
    for(int j=0;j<4;j++){
      uint4 o;
      o.x = (unsigned)f2bf(r[0][j]) | ((unsigned)f2bf(r[1][j])<<16);
      o.y = (unsigned)f2bf(r[2][j]) | ((unsigned)f2bf(r[3][j])<<16);
      o.z = (unsigned)f2bf(r[4][j]) | ((unsigned)f2bf(r[5][j])<<16);
      o.w = (unsigned)f2bf(r[6][j]) | ((unsigned)f2bf(r[7][j])<<16);
      *reinterpret_cast<uint4*>(d + (size_t)j*8) = o;
    }
  }
}

// flat fp32 -> bf16 row-major (for x)
__device__ __forceinline__ void cvt_flat(const float* __restrict__ S,
    unsigned short* __restrict__ D, long ntask, long start, long stride){
  for(long i = start; i < ntask; i += stride){
    const float* p = S + i*8;
    f4v a = __builtin_nontemporal_load((const f4v*)p);
    f4v b = __builtin_nontemporal_load((const f4v*)(p+4));
    uint4 o;
    o.x = (unsigned)f2bf(a[0]) | ((unsigned)f2bf(a[1])<<16);
    o.y = (unsigned)f2bf(a[2]) | ((unsigned)f2bf(a[3])<<16);
    o.z = (unsigned)f2bf(b[0]) | ((unsigned)f2bf(b[1])<<16);
    o.w = (unsigned)f2bf(b[2]) | ((unsigned)f2bf(b[3])<<16);
    *reinterpret_cast<uint4*>(D + i*8) = o;
  }
}

// gate/up weight converts + x convert: 2176 blocks
__global__ __launch_bounds__(256) void k_cvt_gu(
    const float* __restrict__ Wsg, unsigned short* __restrict__ Bsg,
    const float* __restrict__ Wsu, unsigned short* __restrict__ Bsu,
    const float* __restrict__ Wgate, unsigned short* __restrict__ Bgate,
    const float* __restrict__ Wup, unsigned short* __restrict__ Bup,
    const float* __restrict__ x, unsigned short* __restrict__ xb){
  int bid = blockIdx.x, tid = threadIdx.x;
  if(bid < 128)
    cvt_span(Wsg, Bsg, SS, 9, 65536L, (long)bid*256 + tid, 128L*256);
  else if(bid < 256)
    cvt_span(Wsu, Bsu, SS, 9, 65536L, (long)(bid-128)*256 + tid, 128L*256);
  else if(bid < 1152)
    cvt_span(Wgate, Bgate, II, 7, 524288L, (long)(bid-256)*256 + tid, 896L*256);
  else if(bid < 2048)
    cvt_span(Wup, Bup, II, 7, 524288L, (long)(bid-1152)*256 + tid, 896L*256);
  else
    cvt_flat(x, xb, 65536L, (long)(bid-2048)*256 + tid, 128L*256);
}

// ============ DMA-ring GEMM core: C(64x64) += A(64xK)*B(Kx64) ===============
// 4-deep global_load_lds ring, counted vmcnt, K-step 32, 4 waves x 16 rows.
template<bool DUAL>
__device__ __forceinline__ void gemm64(
    const char* aSrc, const char* gSrc, const char* uSrc,
    long bStep, int NK, char* lds, int tid,
    f32x4 (&ag)[4], f32x4 (&au)[4])
{
  const int l = tid&63, w = tid>>6;
  const int mm = l&15, kt = l>>4;
  const int R = w*16 + mm;
  const unsigned aRd = (unsigned)(R*64 + ((kt ^ ((R>>1)&3))<<4));
  const unsigned bRd = (unsigned)(kt*1024 + ((mm ^ (kt<<1))<<4));
  char* aDst = lds + tid*16;
  char* gDst = lds + 16384 + tid*16;
  char* uDst = lds + 32768 + tid*16;

  WAITV(0);   // drain prior stores so counted vmcnt below is exact

#define ISSUE(s_) { const int sl_=(s_)&3;                                   \
    gload16(aSrc + (long)(s_)*64,    aDst + sl_*4096);                      \
    gload16(gSrc + (long)(s_)*bStep, gDst + sl_*4096);                      \
    if(DUAL){ gload16(uSrc + (long)(s_)*bStep, uDst + sl_*4096); } }

  ISSUE(0); ISSUE(1); ISSUE(2);
  for(int s=0; s<NK; s++){
    if(s+3 < NK){
      ISSUE(s+3);
      if constexpr(DUAL){ WAITV(9); } else { WAITV(6); }
    } else if(s+2 < NK){
      if constexpr(DUAL){ WAITV(6); } else { WAITV(4); }
    } else if(s+1 < NK){
      if constexpr(DUAL){ WAITV(3); } else { WAITV(2); }
    } else {
      WAITV(0);
    }
    SBAR();
    {
      const int sl = s&3;
      const char* Ab = lds + sl*4096;
      const char* Gb = lds + 16384 + sl*4096;
      const char* Ub = lds + 32768 + sl*4096;
      s16x8 af = *reinterpret_cast<const s16x8*>(Ab + aRd);
      #pragma unroll
      for(int c=0;c<4;c++){
        s16x8 bg = *reinterpret_cast<const s16x8*>(Gb + bRd + c*256);
        ag[c] = __builtin_amdgcn_mfma_f32_16x16x32_bf16(af, bg, ag[c], 0,0,0);
        if(DUAL){
          s16x8 bu = *reinterpret_cast<const s16x8*>(Ub + bRd + c*256);
          au[c] = __builtin_amdgcn_mfma_f32_16x16x32_bf16(af, bu, au[c], 0,0,0);
        }
      }
    }
    WAITL(); SBAR();
  }
#undef ISSUE
}

// ---------------- launch2: gemm_gu (512) + down-weight cvt (1024) -----------
__global__ __launch_bounds__(256) void k_gu(
    const unsigned short* __restrict__ xb,
    const unsigned short* __restrict__ Bsg, const unsigned short* __restrict__ Bsu,
    unsigned short* __restrict__ Hs,
    const unsigned short* __restrict__ Bgate, const unsigned short* __restrict__ Bup,
    const int* __restrict__ token_list, const int* __restrict__ counts,
    const int* __restrict__ offs, unsigned short* __restrict__ hbuf,
    const float* __restrict__ Wdown, unsigned short* __restrict__ Bdown,
    const float* __restrict__ Wsd, unsigned short* __restrict__ Bsd){
  __shared__ __align__(16) char lds[49152];
  int bid = blockIdx.x, tid = threadIdx.x;
  if(bid >= 512){
    int cb = bid - 512;
    if(cb < 896)
      cvt_span(Wdown, Bdown, HH, 8, 524288L, (long)cb*256 + tid, 896L*256);
    else
      cvt_span(Wsd, Bsd, HH, 8, 65536L, (long)(cb-896)*256 + tid, 128L*256);
    return;
  }
  const int w = tid>>6, l = tid&63;
  const int mm = l&15, kt = l>>4;
  const int ar = tid>>2;
  const int sseg = (tid&3) ^ ((ar>>1)&3);
  const int q = tid>>6, n = tid&63;
  const int nsrc = n ^ (q<<1);
  f32x4 zero = {0.f,0.f,0.f,0.f};
  f32x4 ag[4], au[4];

  if(bid < 256){
    int n0 = (bid & 31) * 64;
    int r0 = (bid >> 5) * 64;
    #pragma unroll
    for(int c=0;c<4;c++){ ag[c]=zero; au[c]=zero; }
    const char* aSrc = (const char*)xb + ((size_t)(r0+ar)*HH + sseg*8)*2;
    const char* gSrc = (const char*)Bsg + ((size_t)q*SS + n0 + nsrc)*16;
    const char* uSrc = (const char*)Bsu + ((size_t)q*SS + n0 + nsrc)*16;
    gemm64<true>(aSrc, gSrc, uSrc, (long)SS*64, HH/32, lds, tid, ag, au);
    #pragma unroll
    for(int c=0;c<4;c++){
      #pragma unroll
      for(int j=0;j<4;j++){
        int lrow = w*16 + kt*4 + j;
        float gg = ag[c][j], uu = au[c][j];
        Hs[(size_t)(r0+lrow)*SS + n0 + c*16 + mm] = f2bf(gg*uu/(1.f+__expf(-gg)));
      }
    }
  } else {
    int g = bid - 256;
    int e = g >> 3, i0 = (g & 7) * 64;
    int cnt = counts[e]; if(cnt == 0) return;
    int off = offs[e];
    const char* gBase = (const char*)(Bgate + (size_t)e*HH*II) + ((size_t)q*II + i0 + nsrc)*16;
    const char* uBase = (const char*)(Bup   + (size_t)e*HH*II) + ((size_t)q*II + i0 + nsrc)*16;
    for(int rt=0; rt*64<cnt; rt++){
      int nv = cnt - rt*64; if(nv > 64) nv = 64;
      int rr_ = ar < nv ? ar : nv-1;
      int tok = token_list[e*TT + rt*64 + rr_];
      #pragma unroll
      for(int c=0;c<4;c++){ ag[c]=zero; au[c]=zero; }
      const char* aSrc = (const char*)xb + ((size_t)tok*HH + sseg*8)*2;
      gemm64<true>(aSrc, gBase, uBase, (long)II*64, HH/32, lds, tid, ag, au);
      #pragma unroll
      for(int c=0;c<4;c++){
        #pragma unroll
        for(int j=0;j<4;j++){
          int lrow = w*16 + kt*4 + j;
          if(lrow < nv){
            float gg = ag[c][j], uu = au[c][j];
            hbuf[(size_t)(off+rt*64+lrow)*II + i0 + c*16 + mm] =
                f2bf(gg*uu/(1.f+__expf(-gg)));
          }
        }
      }
    }
  }
}

// ---------------- launch3: down (shared split-K x2 + expert), atomic --------
__global__ __launch_bounds__(256) void k_down(
    const unsigned short* __restrict__ Hs, const unsigned short* __restrict__ Bsd,
    const float* __restrict__ sig_gate,
    const unsigned short* __restrict__ hbuf, const unsigned short* __restrict__ Bdown,
    const int* __restrict__ token_list, const float* __restrict__ weight_list,
    const int* __restrict__ counts, const int* __restrict__ offs,
    float* __restrict__ out){
  __shared__ __align__(16) char lds[32768];
  int bid = blockIdx.x, tid = threadIdx.x;
  const int w = tid>>6, l = tid&63;
  const int mm = l&15, kt = l>>4;
  const int ar = tid>>2;
  const int sseg = (tid&3) ^ ((ar>>1)&3);
  const int q = tid>>6, n = tid&63;
  const int nsrc = n ^ (q<<1);
  f32x4 zero = {0.f,0.f,0.f,0.f};
  f32x4 acc[4], dummy[4];

  if(bid < 256){
    int rt_ = bid>>5, rem = bid&31;
    int nt_ = rem>>1, kc = rem&1;
    int r0 = rt_*64, n0 = nt_*64;
    #pragma unroll
    for(int c=0;c<4;c++) acc[c]=zero;
    const char* aSrc = (const char*)Hs + ((size_t)(r0+ar)*SS + kc*1024 + sseg*8)*2;
    const char* bSrc = (const char*)Bsd + ((size_t)(kc*128 + q)*HH + n0 + nsrc)*16;
    gemm64<false>(aSrc, bSrc, bSrc, (long)HH*64, 32, lds, tid, acc, dummy);
    #pragma unroll
    for(int c=0;c<4;c++){
      #pragma unroll
      for(int j=0;j<4;j++){
        int lrow = w*16 + kt*4 + j;
        atomicAdd(&out[(size_t)(r0+lrow)*HH + n0 + c*16 + mm],
                  sig_gate[r0+lrow]*acc[c][j]);
      }
    }
  } else {
    int b = bid - 256;
    int e = b >> 4, n0 = (b & 15) * 64;
    int cnt = counts[e]; if(cnt == 0) return;
    int off = offs[e];
    const char* bBase = (const char*)(Bdown + (size_t)e*II*HH) + ((size_t)q*HH + n0 + nsrc)*16;
    for(int rt=0; rt*64<cnt; rt++){
      int nv = cnt - rt*64; if(nv > 64) nv = 64;
      int rr_ = ar < nv ? ar : nv-1;
      #pragma unroll
      for(int c=0;c<4;c++) acc[c]=zero;
      const char* aSrc = (const char*)hbuf + ((size_t)(off+rt*64+rr_)*II + sseg*8)*2;
      gemm64<false>(aSrc, bBase, bBase, (long)HH*64, II/32, lds, tid, acc, dummy);
      #pragma unroll
      for(int c=0;c<4;c++){
        #pragma unroll
        for(int j=0;j<4;j++){
          int lrow = w*16 + kt*4 + j;
          if(lrow < nv){
            int t = token_list[e*TT + rt*64 + lrow];
            float wt = weight_list[e*TT + rt*64 + lrow];
            atomicAdd(&out[(size_t)t*HH + n0 + c*16 + mm], wt*acc[c][j]);
          }
        }
      }
    }
  }
}

extern "C" void kernel_launch(void* const* d_in, const int* in_sizes, int n_in,
                              void* d_out, int out_size, void* d_ws, size_t ws_size,
                              hipStream_t stream) {
  const float* x     = (const float*)d_in[0];
  const float* Wg    = (const float*)d_in[1];
  const float* Wgate = (const float*)d_in[2];
  const float* Wup   = (const float*)d_in[3];
  const float* Wdown = (const float*)d_in[4];
  const float* Wsg   = (const float*)d_in[5];
  const float* Wsu   = (const float*)d_in[6];
  const float* Wsd   = (const float*)d_in[7];
  float* out = (float*)d_out;

  char* ws = (char*)d_ws;
  unsigned short* xb   = (unsigned short*)ws; ws += (size_t)TT*HH*2;
  unsigned short* Hs   = (unsigned short*)ws; ws += (size_t)TT*SS*2;
  unsigned short* hbuf = (unsigned short*)ws; ws += (size_t)(TT*KK+128)*II*2;
  int*   token_list  = (int*)ws;   ws += (size_t)EE*TT*4;
  float* weight_list = (float*)ws; ws += (size_t)EE*TT*4;
  int*   topk_idx    = (int*)ws;   ws += (size_t)TT*KK*4;
  float* topk_wq     = (float*)ws; ws += (size_t)TT*KK*4;
  int*   counts      = (int*)ws;   ws += 128;
  int*   offsb       = (int*)ws;   ws += 128;
  float* sig_gate    = (float*)ws; ws += (size_t)TT*4;
  unsigned short* Bsg   = (unsigned short*)ws; ws += (size_t)HH*SS*2;
  unsigned short* Bsu   = (unsigned short*)ws; ws += (size_t)HH*SS*2;
  unsigned short* Bgate = (unsigned short*)ws; ws += (size_t)EE*HH*II*2;
  unsigned short* Bup   = (unsigned short*)ws; ws += (size_t)EE*HH*II*2;
  unsigned short* Bdown = (unsigned short*)ws; ws += (size_t)EE*II*HH*2;
  unsigned short* Bsd   = (unsigned short*)ws; ws += (size_t)SS*HH*2;

  hipMemsetAsync(d_out, 0, (size_t)TT*HH*4, stream);
  k_router<<<TT, 256, 0, stream>>>(x, Wg, topk_idx, topk_wq, sig_gate);
  k_build<<<EE, 64, 0, stream>>>(topk_idx, topk_wq, token_list, weight_list, counts);
  k_scan<<<1, 64, 0, stream>>>(counts, offsb);
  k_cvt_gu<<<2176, 256, 0, stream>>>(Wsg, Bsg, Wsu, Bsu, Wgate, Bgate, Wup, Bup, x, xb);
  k_gu<<<512 + 1024, 256, 0, stream>>>(
      xb, Bsg, Bsu, Hs, Bgate, Bup, token_list, counts, offsb, hbuf,
      Wdown, Bdown, Wsd, Bsd);
  k_down<<<256 + EE*(HH/64), 256, 0, stream>>>(
      Hs, Bsd, sig_gate, hbuf, Bdown, token_list, weight_list, counts, offsb, out);
}